// Round 8
// baseline (176.183 us; speedup 1.0000x reference)
//
#include <hip/hip_runtime.h>

#define IMG_H 512
#define IMG_W 512
#define HW (IMG_H * IMG_W)
#define NB 32
#define NSX 64              // grid.x: 32 row-strips x 2 column halves
#define RPW 4               // rows per wave (block covers 16 rows x 256 cols)
#define DSLOT (HW / NSX)    // depth floats per slot (4096)

// Workspace: per-(image,slot) partials, no atomics, no memset (re-poison safe:
// every slot written each iteration). Slot = blockIdx.x in [0,64).
#define ACCP_DOUBLES (5 * NB * NSX)
#define HISTP_U32 (NB * NSX * 256)
#define WS_BYTES (ACCP_DOUBLES * 8 + HISTP_U32 * 4)

// Structure log (hard-won, do not revisit):
// - RING beats LDS-tile: tile (r5) = 71.5us vs ring ~52-54us (phase convoy).
// - Two-kernel split: in-kernel finalization w/ fences = 3.6x regression (r1-r2).
// - Per-wave lh[4][256]: single shared lh[256] tripled LDS bank conflicts (r5).
// - (256,4) with the FULL-width ring (150-float state) spilled 111 MB (r1).
// - Round 7 bench was an infra failure (container), not a kernel verdict;
//   this is the same half-width experiment resubmitted.
// HALF-WIDTH ring designed for the 64-VGPR clamp: lane owns 4 columns
// (3 float4/row-load), RPW=4 (1.5x halo traffic, r4's best ratio), ring
// depth 1, depth staged 4x float4 consumed one/iter. Peak live ~55 floats
// -> (256,4) should fit WITHOUT spilling -> 8 waves/SIMD (2x occupancy cap).
// WATCH: WRITE_SIZE >= 20 MB means spill -> revert to (256,2) full-width.
struct RowH { float4 a, b, c; };

__device__ inline RowH load_rowh(const float* __restrict__ rp, int r, int c0) {
    RowH x;
    if ((unsigned)r < IMG_H) {          // wave-uniform branch
        const size_t o = (size_t)r * IMG_W + c0;
        x.a = *(const float4*)(rp + o);
        x.b = *(const float4*)(rp + HW + o);
        x.c = *(const float4*)(rp + 2 * HW + o);
    } else {
        const float4 z = {0.f, 0.f, 0.f, 0.f};
        x.a = x.b = x.c = z;
    }
    return x;
}

__device__ inline void to_gray4(const RowH& x, float g[4]) {
    g[0] = 0.299f * x.a.x + 0.587f * x.b.x + 0.114f * x.c.x;
    g[1] = 0.299f * x.a.y + 0.587f * x.b.y + 0.114f * x.c.y;
    g[2] = 0.299f * x.a.z + 0.587f * x.b.z + 0.114f * x.c.z;
    g[3] = 0.299f * x.a.w + 0.587f * x.b.w + 0.114f * x.c.w;
}

// Uniform-address gray load of the seam column (1 cache line, broadcast).
__device__ inline float edge_gray(const float* __restrict__ rp, int r, int ecol) {
    if ((unsigned)r < IMG_H) {
        const size_t o = (size_t)r * IMG_W + ecol;
        return 0.299f * rp[o] + 0.587f * rp[HW + o] + 0.114f * rp[2 * HW + o];
    }
    return 0.f;
}

__global__ __launch_bounds__(256, 4) void fused_kernel(
    const float* __restrict__ rgb, const float* __restrict__ depth,
    double* __restrict__ accp, unsigned int* __restrict__ histp)
{
    __shared__ unsigned int lh[4][256];
    __shared__ double red[4][5];

    const int t = threadIdx.x;
    const int b = blockIdx.y;
    const int x = blockIdx.x;
    const int rs = x >> 1;              // row strip 0..31 (16 rows each)
    const int h  = x & 1;               // column half
    const int lane = t & 63;
    const int w = t >> 6;

    #pragma unroll
    for (int i = 0; i < 4; ++i) lh[i][t] = 0u;
    __syncthreads();

    const float* rp = rgb + (size_t)b * 3 * HW;
    const int rb = rs * 16 + w * RPW;   // first owned row
    const int c0 = h * 256 + lane * 4;  // first owned column
    const int ecol = h ? 255 : 256;     // seam neighbor column

    const float4* dp = (const float4*)(depth + (size_t)b * HW + (size_t)x * DSLOT);

    // ---- prologue: 3 half-rows + seam edges + 4 depth float4 in flight ----
    RowH r0 = load_rowh(rp, rb - 1, c0);
    RowH r1 = load_rowh(rp, rb,     c0);
    RowH stg = load_rowh(rp, rb + 1, c0);
    float ec = edge_gray(rp, rb,     ecol);   // seam gray of center row
    float en = edge_gray(rp, rb + 1, ecol);
    float4 dv[4];
    #pragma unroll
    for (int k = 0; k < 4; ++k) dv[k] = dp[k * 256 + t];

    float gp[4], gc[4], gn[4];
    to_gray4(r0, gp);
    to_gray4(r1, gc);

    float s1 = 0.f, s2 = 0.f;
    float dnf = 0.f, dsf = 0.f, dqf = 0.f;

    #pragma unroll
    for (int r = 0; r < RPW; ++r) {
        to_gray4(stg, gn);
        float etmp = 0.f;
        if (r < RPW - 1) {              // refill: row rb+r+2 (consumed next iter)
            stg = load_rowh(rp, rb + r + 2, c0);
            etmp = edge_gray(rp, rb + r + 2, ecol);
        }

        // seam handling: lane0's left / lane63's right come from ec or image pad
        float lf = __shfl_up(gc[3], 1, 64);
        if (lane == 0)  lf = h ? ec : 0.f;
        float rt = __shfl_down(gc[0], 1, 64);
        if (lane == 63) rt = h ? 0.f : ec;

        #pragma unroll
        for (int j = 0; j < 4; ++j) {
            const float left  = (j == 0) ? lf : gc[j - 1];
            const float right = (j == 3) ? rt : gc[j + 1];
            const float lap = gp[j] + gn[j] + left + right - 4.f * gc[j];
            s1 += lap;
            s2 += lap * lap;
            atomicAdd(&lh[w][(int)fminf(fmaxf(gc[j] * 255.f, 0.f), 255.f)], 1u);
        }

        // consume one depth vector per iteration (registers free progressively)
        const float4 d = dv[r];
        if (d.x > 0.f) { dnf += 1.f; dsf += d.x; dqf += d.x * d.x; }
        if (d.y > 0.f) { dnf += 1.f; dsf += d.y; dqf += d.y * d.y; }
        if (d.z > 0.f) { dnf += 1.f; dsf += d.z; dqf += d.z * d.z; }
        if (d.w > 0.f) { dnf += 1.f; dsf += d.w; dqf += d.w * d.w; }

        #pragma unroll
        for (int j = 0; j < 4; ++j) { gp[j] = gc[j]; gc[j] = gn[j]; }
        ec = en; en = etmp;
    }

    // ---- block reduction of the 5 scalars ----
    double z0 = (double)s1, z1 = (double)s2, z2 = (double)dnf, z3 = (double)dsf, z4 = (double)dqf;
    for (int off = 32; off > 0; off >>= 1) {
        z0 += __shfl_down(z0, off, 64);
        z1 += __shfl_down(z1, off, 64);
        z2 += __shfl_down(z2, off, 64);
        z3 += __shfl_down(z3, off, 64);
        z4 += __shfl_down(z4, off, 64);
    }
    if (lane == 0) {
        red[w][0] = z0; red[w][1] = z1; red[w][2] = z2; red[w][3] = z3; red[w][4] = z4;
    }
    __syncthreads();   // covers lh writes and red[] writes

    // ---- disjoint partial stores (coalesced, no global atomics) ----
    const unsigned int hsum = lh[0][t] + lh[1][t] + lh[2][t] + lh[3][t];
    histp[((size_t)b * NSX + x) * 256 + t] = hsum;
    if (t < 5) {
        const double v = red[0][t] + red[1][t] + red[2][t] + red[3][t];
        accp[((size_t)t * NB + b) * NSX + x] = v;
    }
}

// One block per image: reduce the 64 slot-partials, entropy, final scores.
__global__ __launch_bounds__(256) void final_kernel(
    const double* __restrict__ accp,
    const unsigned int* __restrict__ histp,
    float* __restrict__ out)
{
    __shared__ float ent[4];
    __shared__ double sacc[5];

    const int t = threadIdx.x;
    const int b = blockIdx.x;
    const int lane = t & 63;
    const int w = t >> 6;

    unsigned int hv = 0u;
    #pragma unroll
    for (int s = 0; s < NSX; ++s)
        hv += histp[((size_t)b * NSX + s) * 256 + t];

    const float p = (float)hv * (1.0f / (float)HW);
    float term = p * log2f(p + 1e-4f);
    for (int off = 32; off > 0; off >>= 1) term += __shfl_down(term, off, 64);
    if (lane == 0) ent[w] = term;

    // 5 scalar sums over 64 slots: 32-thread group per scalar, 2 values/thread
    if (t < 160) {
        const int k = t >> 5, ss = t & 31;
        double v = accp[((size_t)k * NB + b) * NSX + ss]
                 + accp[((size_t)k * NB + b) * NSX + ss + 32];
        for (int off = 16; off > 0; off >>= 1) v += __shfl_down(v, off, 32);
        if (ss == 0) sacc[k] = v;
    }
    __syncthreads();

    if (t == 0) {
        const double entropy = -(double)(ent[0] + ent[1] + ent[2] + ent[3]);
        const double N = (double)HW;

        const double ls = sacc[0], lq = sacc[1];
        const double lvar = (lq - ls * ls / N) / (N - 1.0);
        const double clarity = lvar / (1000.0 + 1e-4);
        const double uniformity = 1.0 / (entropy + 1e-4);
        const double rgb_conf = 0.5 * (clarity + uniformity);

        const double n = sacc[2], sdep = sacc[3], q = sacc[4];
        const double mean = sdep / fmax(n, 1.0);
        const double sq = q - 2.0 * mean * sdep + mean * mean * n;
        const double var = sq / fmax(n - 1.0, 1.0);
        const double stdd = sqrt(fmax(var, 0.0));
        const double noise = (n > 0.0) ? stdd : 1.0;
        const double density = n / N;
        const double depth_conf = 0.5 * (density / (10000.0 + 1e-4) + 1.0 / (noise + 1e-4));

        const double denom = rgb_conf + depth_conf + 1e-4;
        out[b]      = (float)(rgb_conf / denom);
        out[NB + b] = (float)(depth_conf / denom);
    }
}

extern "C" void kernel_launch(void* const* d_in, const int* in_sizes, int n_in,
                              void* d_out, int out_size, void* d_ws, size_t ws_size,
                              hipStream_t stream) {
    const float* rgb   = (const float*)d_in[0];
    const float* depth = (const float*)d_in[1];
    float* out = (float*)d_out;

    double* accp = (double*)d_ws;
    unsigned int* histp = (unsigned int*)((char*)d_ws + ACCP_DOUBLES * 8);

    fused_kernel<<<dim3(NSX, NB), 256, 0, stream>>>(rgb, depth, accp, histp);
    final_kernel<<<NB, 256, 0, stream>>>(accp, histp, out);
}

// Round 9
// 172.604 us; speedup vs baseline: 1.0207x; 1.0207x over previous
//
#include <hip/hip_runtime.h>

#define IMG_H 512
#define IMG_W 512
#define HW (IMG_H * IMG_W)
#define NB 32
#define STRIPS 64           // blocks per image; block = 4 waves x 2 rows = 8 rows
#define RPW 2               // rows per wave

// Workspace: per-(image,slot) partials, no atomics, no memset (re-poison safe:
// every slot written each iteration).
#define ACCP_DOUBLES (5 * NB * STRIPS)
#define HISTP_U32 (NB * STRIPS * 256)
#define WS_BYTES (ACCP_DOUBLES * 8 + HISTP_U32 * 4)

struct Row6 { float4 a0, a1, b0, b1, c0, c1; };

__device__ inline Row6 load_row(const float* __restrict__ rp, int r, int c0) {
    Row6 x;
    if ((unsigned)r < IMG_H) {          // wave-uniform branch
        const size_t o = (size_t)r * IMG_W + c0;
        x.a0 = *(const float4*)(rp + o);
        x.a1 = *(const float4*)(rp + o + 4);
        x.b0 = *(const float4*)(rp + HW + o);
        x.b1 = *(const float4*)(rp + HW + o + 4);
        x.c0 = *(const float4*)(rp + 2 * HW + o);
        x.c1 = *(const float4*)(rp + 2 * HW + o + 4);
    } else {
        const float4 z = {0.f, 0.f, 0.f, 0.f};
        x.a0 = x.a1 = x.b0 = x.b1 = x.c0 = x.c1 = z;
    }
    return x;
}

__device__ inline void to_gray(const Row6& x, float g[8]) {
    g[0] = 0.299f * x.a0.x + 0.587f * x.b0.x + 0.114f * x.c0.x;
    g[1] = 0.299f * x.a0.y + 0.587f * x.b0.y + 0.114f * x.c0.y;
    g[2] = 0.299f * x.a0.z + 0.587f * x.b0.z + 0.114f * x.c0.z;
    g[3] = 0.299f * x.a0.w + 0.587f * x.b0.w + 0.114f * x.c0.w;
    g[4] = 0.299f * x.a1.x + 0.587f * x.b1.x + 0.114f * x.c1.x;
    g[5] = 0.299f * x.a1.y + 0.587f * x.b1.y + 0.114f * x.c1.y;
    g[6] = 0.299f * x.a1.z + 0.587f * x.b1.z + 0.114f * x.c1.z;
    g[7] = 0.299f * x.a1.w + 0.587f * x.b1.w + 0.114f * x.c1.w;
}

// Structure log (hard-won, do not revisit):
// - RING beats full LDS-tile: tile (r5) = 71.5us vs ring ~52us (phase convoy).
// - Two-kernel split: in-kernel finalization w/ fences = 3.6x regression (r1-r2).
// - Per-wave lh[4][256]: single shared lh[256] tripled LDS bank conflicts (r5).
// - (256,4) full-width ring spilled 111 MB (r1). (256,2) is the no-spill build.
// - OCCUPANCY IS NOT THE CONSTRAINT: r8 hit VGPR=48 (8 waves/SIMD capable),
//   zero spill, and was SLOWER (59 vs 52us). Do not chase occupancy again.
// This round: keep r6's skeleton exactly (full-width lanes, STRIPS=64, XCD
// swizzle, (256,2)) but cut rgb halo traffic 2.0x -> 1.25x: each wave loads
// only its 2 interior rows; +-1 halo GRAYS come from neighbor waves via LDS
// (one barrier). Block-edge waves (w=0,3) load one extra global row. Depth
// loads issued pre-barrier, consumed post-barrier (memory busy across phases).
__global__ __launch_bounds__(256, 2) void fused_kernel(
    const float* __restrict__ rgb, const float* __restrict__ depth,
    double* __restrict__ accp, unsigned int* __restrict__ histp)
{
    __shared__ float gtop[4][512];      // wave w's first (upper) gray row
    __shared__ float gbot[4][512];      // wave w's last (lower) gray row
    __shared__ unsigned int lh[4][256];
    __shared__ double red[4][5];

    const int t = threadIdx.x;
    const int b = blockIdx.y;
    const int x = blockIdx.x;
    const int s = ((x & 7) << 3) | (x >> 3);   // bijective on [0,64): XCD-local halos
    const int lane = t & 63;
    const int w = t >> 6;

    #pragma unroll
    for (int i = 0; i < 4; ++i) lh[i][t] = 0u;   // covered by the one barrier below

    const float* rp = rgb + (size_t)b * 3 * HW;
    const int rb = s * 8 + w * RPW;     // first owned row
    const int c0 = lane * 8;            // first owned column

    const float4* dp = (const float4*)(depth + (size_t)b * HW + (size_t)s * (HW / STRIPS));

    // ---- phase A: interior loads + boundary-halo loads + depth, then gray ----
    Row6 rA = load_row(rp, rb,     c0);
    Row6 rB = load_row(rp, rb + 1, c0);
    Row6 rT, rD;                         // block-edge halo rows (wave-uniform branch)
    if (w == 0) rT = load_row(rp, rb - 1, c0);
    if (w == 3) rD = load_row(rp, rb + 2, c0);
    float4 dv[4];
    #pragma unroll
    for (int k = 0; k < 4; ++k) dv[k] = dp[k * 256 + t];

    float ga[8], gb[8];
    to_gray(rA, ga);
    to_gray(rB, gb);
    #pragma unroll
    for (int j = 0; j < 8; ++j) { gtop[w][c0 + j] = ga[j]; gbot[w][c0 + j] = gb[j]; }

    float gt[8], gd[8];                  // register halos for edge waves
    if (w == 0) to_gray(rT, gt);
    if (w == 3) to_gray(rD, gd);

    __syncthreads();   // publishes gtop/gbot + lh zeros

    // ---- phase B: fetch halo grays, laplacian, histogram, depth stats ----
    float ha[8], hb[8];                  // gray(rb-1), gray(rb+2)
    if (w == 0) {
        #pragma unroll
        for (int j = 0; j < 8; ++j) ha[j] = gt[j];
    } else {
        #pragma unroll
        for (int j = 0; j < 8; ++j) ha[j] = gbot[w - 1][c0 + j];
    }
    if (w == 3) {
        #pragma unroll
        for (int j = 0; j < 8; ++j) hb[j] = gd[j];
    } else {
        #pragma unroll
        for (int j = 0; j < 8; ++j) hb[j] = gtop[w + 1][c0 + j];
    }

    float s1 = 0.f, s2 = 0.f;
    float dnf = 0.f, dsf = 0.f, dqf = 0.f;

    // row rb: up = ha, center = ga, down = gb
    {
        float lf = __shfl_up(ga[7], 1, 64);
        if (lane == 0) lf = 0.f;
        float rt = __shfl_down(ga[0], 1, 64);
        if (lane == 63) rt = 0.f;
        #pragma unroll
        for (int j = 0; j < 8; ++j) {
            const float left  = (j == 0) ? lf : ga[j - 1];
            const float right = (j == 7) ? rt : ga[j + 1];
            const float lap = ha[j] + gb[j] + left + right - 4.f * ga[j];
            s1 += lap;
            s2 += lap * lap;
            atomicAdd(&lh[w][(int)fminf(fmaxf(ga[j] * 255.f, 0.f), 255.f)], 1u);
        }
    }
    // row rb+1: up = ga, center = gb, down = hb
    {
        float lf = __shfl_up(gb[7], 1, 64);
        if (lane == 0) lf = 0.f;
        float rt = __shfl_down(gb[0], 1, 64);
        if (lane == 63) rt = 0.f;
        #pragma unroll
        for (int j = 0; j < 8; ++j) {
            const float left  = (j == 0) ? lf : gb[j - 1];
            const float right = (j == 7) ? rt : gb[j + 1];
            const float lap = ga[j] + hb[j] + left + right - 4.f * gb[j];
            s1 += lap;
            s2 += lap * lap;
            atomicAdd(&lh[w][(int)fminf(fmaxf(gb[j] * 255.f, 0.f), 255.f)], 1u);
        }
    }

    #pragma unroll
    for (int k = 0; k < 4; ++k) {
        const float4 d = dv[k];
        if (d.x > 0.f) { dnf += 1.f; dsf += d.x; dqf += d.x * d.x; }
        if (d.y > 0.f) { dnf += 1.f; dsf += d.y; dqf += d.y * d.y; }
        if (d.z > 0.f) { dnf += 1.f; dsf += d.z; dqf += d.z * d.z; }
        if (d.w > 0.f) { dnf += 1.f; dsf += d.w; dqf += d.w * d.w; }
    }

    // ---- block reduction of the 5 scalars ----
    double z0 = (double)s1, z1 = (double)s2, z2 = (double)dnf, z3 = (double)dsf, z4 = (double)dqf;
    for (int off = 32; off > 0; off >>= 1) {
        z0 += __shfl_down(z0, off, 64);
        z1 += __shfl_down(z1, off, 64);
        z2 += __shfl_down(z2, off, 64);
        z3 += __shfl_down(z3, off, 64);
        z4 += __shfl_down(z4, off, 64);
    }
    if (lane == 0) {
        red[w][0] = z0; red[w][1] = z1; red[w][2] = z2; red[w][3] = z3; red[w][4] = z4;
    }
    __syncthreads();   // covers lh writes and red[] writes

    // ---- disjoint partial stores (coalesced, no global atomics) ----
    const unsigned int hsum = lh[0][t] + lh[1][t] + lh[2][t] + lh[3][t];
    histp[((size_t)b * STRIPS + s) * 256 + t] = hsum;
    if (t < 5) {
        const double v = red[0][t] + red[1][t] + red[2][t] + red[3][t];
        accp[((size_t)t * NB + b) * STRIPS + s] = v;
    }
}

// One block per image: reduce the 64 slot-partials, entropy, final scores.
__global__ __launch_bounds__(256) void final_kernel(
    const double* __restrict__ accp,
    const unsigned int* __restrict__ histp,
    float* __restrict__ out)
{
    __shared__ float ent[4];
    __shared__ double sacc[5];

    const int t = threadIdx.x;
    const int b = blockIdx.x;
    const int lane = t & 63;
    const int w = t >> 6;

    unsigned int hv = 0u;
    #pragma unroll
    for (int s = 0; s < STRIPS; ++s)
        hv += histp[((size_t)b * STRIPS + s) * 256 + t];

    const float p = (float)hv * (1.0f / (float)HW);
    float term = p * log2f(p + 1e-4f);
    for (int off = 32; off > 0; off >>= 1) term += __shfl_down(term, off, 64);
    if (lane == 0) ent[w] = term;

    // 5 scalar sums over 64 slots: 32-thread group per scalar, 2 values/thread
    if (t < 160) {
        const int k = t >> 5, ss = t & 31;
        double v = accp[((size_t)k * NB + b) * STRIPS + ss]
                 + accp[((size_t)k * NB + b) * STRIPS + ss + 32];
        for (int off = 16; off > 0; off >>= 1) v += __shfl_down(v, off, 32);
        if (ss == 0) sacc[k] = v;
    }
    __syncthreads();

    if (t == 0) {
        const double entropy = -(double)(ent[0] + ent[1] + ent[2] + ent[3]);
        const double N = (double)HW;

        const double ls = sacc[0], lq = sacc[1];
        const double lvar = (lq - ls * ls / N) / (N - 1.0);
        const double clarity = lvar / (1000.0 + 1e-4);
        const double uniformity = 1.0 / (entropy + 1e-4);
        const double rgb_conf = 0.5 * (clarity + uniformity);

        const double n = sacc[2], sdep = sacc[3], q = sacc[4];
        const double mean = sdep / fmax(n, 1.0);
        const double sq = q - 2.0 * mean * sdep + mean * mean * n;
        const double var = sq / fmax(n - 1.0, 1.0);
        const double stdd = sqrt(fmax(var, 0.0));
        const double noise = (n > 0.0) ? stdd : 1.0;
        const double density = n / N;
        const double depth_conf = 0.5 * (density / (10000.0 + 1e-4) + 1.0 / (noise + 1e-4));

        const double denom = rgb_conf + depth_conf + 1e-4;
        out[b]      = (float)(rgb_conf / denom);
        out[NB + b] = (float)(depth_conf / denom);
    }
}

extern "C" void kernel_launch(void* const* d_in, const int* in_sizes, int n_in,
                              void* d_out, int out_size, void* d_ws, size_t ws_size,
                              hipStream_t stream) {
    const float* rgb   = (const float*)d_in[0];
    const float* depth = (const float*)d_in[1];
    float* out = (float*)d_out;

    double* accp = (double*)d_ws;
    unsigned int* histp = (unsigned int*)((char*)d_ws + ACCP_DOUBLES * 8);

    fused_kernel<<<dim3(STRIPS, NB), 256, 0, stream>>>(rgb, depth, accp, histp);
    final_kernel<<<NB, 256, 0, stream>>>(accp, histp, out);
}